// Round 15
// baseline (117.906 us; speedup 1.0000x reference)
//
#include <hip/hip_runtime.h>
#include <hip/hip_bf16.h>

constexpr int B_  = 2;
constexpr int T_  = 2048;
constexpr int D_  = 1024;
constexpr int H_  = 16;
constexpr int DK_ = 64;
// exp(s/8) == exp2(s * log2(e)/8); this factor is baked into Qb.
#define SC_EXP 0.18033688011112042591f

typedef __attribute__((ext_vector_type(8))) short bhalf8;
typedef __attribute__((ext_vector_type(4))) float f32x4;

__device__ __forceinline__ f32x4 mfma16(bhalf8 a, bhalf8 b, f32x4 c) {
  return __builtin_amdgcn_mfma_f32_16x16x32_bf16(a, b, c, 0, 0, 0);
}

__device__ __forceinline__ void g2l16(const void* g, void* l) {
  __builtin_amdgcn_global_load_lds((const __attribute__((address_space(1))) void*)g,
                                   (__attribute__((address_space(3))) void*)l, 16, 0, 0);
}

// Raw barrier + scheduling fence (rule #18): no vmcnt drain.
#define BAR_FENCE() do { __builtin_amdgcn_s_barrier(); \
                         __builtin_amdgcn_sched_barrier(0); } while (0)

// XCD-aware bijective block swizzle (nwg must be a multiple of 8).
template<int NWG>
__device__ __forceinline__ int xcd_swz(int bid) {
  return (bid & 7) * (NWG / 8) + (bid >> 3);
}

// Stage ROWS x 128B (64 bf16) tile from global into LDS, slot-XOR swizzled.
// Source is pre-swizzled so the linear global_load_lds dest ends up swizzled.
template<int ROWS, int NT>
__device__ __forceinline__ void stage_swz(const char* gbase, int gstride,
                                          char* lds, int tid) {
  const int wave = tid >> 6;
  constexpr int CHUNKS = ROWS * 8;  // 16B chunks
  #pragma unroll
  for (int j = 0; j < CHUNKS / NT; ++j) {
    int c = j * NT + tid;
    int row = c >> 3, slot = c & 7;
    g2l16(gbase + (size_t)row * gstride + ((slot ^ (row & 7)) << 4),
          lds + (j * NT + wave * 64) * 16);
  }
}

// Read one 16x32 MFMA fragment (A or B^T layout) from a swizzled [rows][128B] tile.
__device__ __forceinline__ bhalf8 frag_ld(const char* tile, int row, int kbyte, int lane) {
  int r = row + (lane & 15);
  int off = kbyte + ((lane >> 4) << 4);
  off ^= (r & 7) << 4;
  return *(const bhalf8*)(tile + r * 128 + off);
}

// Convert 8 f32 -> bf16 and store to swizzled LDS tile position.
__device__ __forceinline__ void cvt8_store(char* lds, int row, int slot, const float* f) {
  union { bhalf8 v; __hip_bfloat16 h[8]; } u;
  #pragma unroll
  for (int i = 0; i < 8; ++i) u.h[i] = __float2bfloat16(f[i]);
  *(bhalf8*)(lds + row * 128 + ((slot ^ (row & 7)) << 4)) = u.v;
}

// ---------------- fused prep: q,k bf16 casts + 4 weight transposes + ctx zero.
__global__ __launch_bounds__(256) void prep(const float* __restrict__ q,
    const float* __restrict__ k, const float* __restrict__ Wq,
    const float* __restrict__ Wk, const float* __restrict__ Wo,
    const float* __restrict__ Wv, __hip_bfloat16* __restrict__ qb,
    __hip_bfloat16* __restrict__ kb, __hip_bfloat16* __restrict__ Wqt,
    __hip_bfloat16* __restrict__ Wkt, __hip_bfloat16* __restrict__ Wot,
    __hip_bfloat16* __restrict__ Wvt, float* __restrict__ ctx) {
  __shared__ float t[32][33];
  int bid = blockIdx.x;
  if (bid < 4096) {
    const float* s = bid < 2048 ? q : k;
    __hip_bfloat16* d = bid < 2048 ? qb : kb;
    int i = (bid & 2047) * 256 + threadIdx.x;
    const float4* sp = (const float4*)(s + (size_t)i * 8);
    float4 f0 = sp[0], f1 = sp[1];
    union { bhalf8 v; __hip_bfloat16 h[8]; } u;
    u.h[0] = __float2bfloat16(f0.x); u.h[1] = __float2bfloat16(f0.y);
    u.h[2] = __float2bfloat16(f0.z); u.h[3] = __float2bfloat16(f0.w);
    u.h[4] = __float2bfloat16(f1.x); u.h[5] = __float2bfloat16(f1.y);
    u.h[6] = __float2bfloat16(f1.z); u.h[7] = __float2bfloat16(f1.w);
    *(bhalf8*)(d + (size_t)i * 8) = u.v;
    return;
  }
  if (bid >= 6272) {
    // zero ctx: 512 blocks x 256 threads x 16B = 2 MB
    int i = (bid - 6272) * 256 + threadIdx.x;
    ((f32x4*)ctx)[i] = (f32x4){0.f, 0.f, 0.f, 0.f};
    return;
  }
  bid -= 4096;
  const float* src; __hip_bfloat16* dst; int R, C, bx, by;
  if (bid < 1024)      { src = Wq; dst = Wqt; R = 1024; C = 1024; bx = bid & 31; by = bid >> 5; }
  else if (bid < 2048) { bid -= 1024; src = Wk; dst = Wkt; R = 1024; C = 1024; bx = bid & 31; by = bid >> 5; }
  else if (bid < 2112) { bid -= 2048; src = Wo; dst = Wot; R = 64;   C = 1024; bx = bid & 31; by = bid >> 5; }
  else                 { bid -= 2112; src = Wv; dst = Wvt; R = 1024; C = 64;   bx = bid & 1;  by = bid >> 1; }
  const int tx = threadIdx.x & 31, ty = threadIdx.x >> 5;
  const int c0 = bx * 32, r0 = by * 32;
  #pragma unroll
  for (int i = 0; i < 32; i += 8)
    t[ty + i][tx] = src[(size_t)(r0 + ty + i) * C + c0 + tx];
  __syncthreads();
  #pragma unroll
  for (int i = 0; i < 32; i += 8)
    dst[(size_t)(c0 + ty + i) * R + r0 + tx] = __float2bfloat16(t[tx][ty + i]);
}

// ---------------- Q/K/V projections in ONE launch (blockIdx.z: 0=Q, 1=K, 2=V).
__global__ __launch_bounds__(256) void proj_all(const __hip_bfloat16* __restrict__ qb,
    const __hip_bfloat16* __restrict__ kb, const float* __restrict__ v,
    const __hip_bfloat16* __restrict__ Wqt, const __hip_bfloat16* __restrict__ Wkt,
    const __hip_bfloat16* __restrict__ Wvt, const float* __restrict__ bq,
    const float* __restrict__ bk, __hip_bfloat16* __restrict__ Qb,
    __hip_bfloat16* __restrict__ Kb, float* __restrict__ Vf_part) {
  __shared__ char At[2][128 * 128];
  __shared__ char Bt[2][128 * 128];
  const int tid = threadIdx.x, lane = tid & 63, wave = tid >> 6;
  const int g = lane >> 4, cl = lane & 15;

  if (blockIdx.z == 2) {
    // ---- V projection, split-K partials: Vf_part[ky][4096][64]
    const int m0 = (blockIdx.x & 31) * 128;
    const int ky = blockIdx.x >> 5;
    const int k0base = ky * 128;
    const int wr = (wave >> 1) * 64, wc = (wave & 1) * 32;
    stage_swz<64, 256>((const char*)(Wvt + k0base), D_ * 2, Bt[0], tid);
    stage_swz<64, 256>((const char*)(Wvt + k0base + 64), D_ * 2, Bt[1], tid);
    #pragma unroll
    for (int half = 0; half < 2; ++half) {
      const int k0 = k0base + half * 64;
      #pragma unroll
      for (int j = 0; j < 4; ++j) {
        int c = tid + j * 256;
        int row = c >> 3, slot = c & 7;
        const float* src = v + (size_t)(m0 + row) * D_ + k0 + slot * 8;
        float f[8];
        *(float4*)f       = *(const float4*)src;
        *(float4*)(f + 4) = *(const float4*)(src + 4);
        cvt8_store(At[half], row, slot, f);
      }
    }
    __syncthreads();
    f32x4 acc[4][2] = {};
    #pragma unroll
    for (int kk = 0; kk < 2; ++kk) {
      bhalf8 a[4][2], bb[2][2];
      #pragma unroll
      for (int mi = 0; mi < 4; ++mi)
        #pragma unroll
        for (int ks = 0; ks < 2; ++ks)
          a[mi][ks] = frag_ld(At[kk], wr + mi * 16, ks * 64, lane);
      #pragma unroll
      for (int ni = 0; ni < 2; ++ni)
        #pragma unroll
        for (int ks = 0; ks < 2; ++ks)
          bb[ni][ks] = frag_ld(Bt[kk], wc + ni * 16, ks * 64, lane);
      #pragma unroll
      for (int mi = 0; mi < 4; ++mi)
        #pragma unroll
        for (int ni = 0; ni < 2; ++ni) {
          acc[mi][ni] = mfma16(a[mi][0], bb[ni][0], acc[mi][ni]);
          acc[mi][ni] = mfma16(a[mi][1], bb[ni][1], acc[mi][ni]);
        }
    }
    float* dst = Vf_part + (size_t)ky * (B_ * T_ * DK_);
    #pragma unroll
    for (int mi = 0; mi < 4; ++mi)
      #pragma unroll
      for (int ni = 0; ni < 2; ++ni)
        #pragma unroll
        for (int r = 0; r < 4; ++r) {
          int m = m0 + wr + mi * 16 + g * 4 + r;
          int n = wc + ni * 16 + cl;
          dst[(size_t)m * DK_ + n] = acc[mi][ni][r];
        }
    return;
  }

  // ---- Q / K projection
  const bool isk = blockIdx.z != 0;
  const __hip_bfloat16* A  = isk ? kb : qb;
  const __hip_bfloat16* Wt = isk ? Wkt : Wqt;
  const float* bias        = isk ? bk : bq;
  __hip_bfloat16* C        = isk ? Kb : Qb;
  const float scale        = isk ? 1.0f : SC_EXP;
  const int id = xcd_swz<256>(blockIdx.x);
  const int m0 = (id & 31) * 128, n0 = (id >> 5) * 128;
  const int wr = (wave >> 1) * 64, wc = (wave & 1) * 64;
  f32x4 acc[4][4] = {};
  stage_swz<128, 256>((const char*)(A + (size_t)m0 * D_), D_ * 2, At[0], tid);
  stage_swz<128, 256>((const char*)(Wt + (size_t)n0 * D_), D_ * 2, Bt[0], tid);
  __syncthreads();
  int cur = 0;
  for (int k0 = 0; k0 < 16; ++k0) {
    if (k0 + 1 < 16) {
      stage_swz<128, 256>((const char*)(A + (size_t)m0 * D_ + (k0 + 1) * 64), D_ * 2, At[cur ^ 1], tid);
      stage_swz<128, 256>((const char*)(Wt + (size_t)n0 * D_ + (k0 + 1) * 64), D_ * 2, Bt[cur ^ 1], tid);
      asm volatile("s_waitcnt vmcnt(8)" ::: "memory");
    } else {
      asm volatile("s_waitcnt vmcnt(0)" ::: "memory");
    }
    BAR_FENCE();
    bhalf8 a[4], b[4];
    #pragma unroll
    for (int mi = 0; mi < 4; ++mi) {
      a[mi] = frag_ld(At[cur], wr + mi * 16, 0, lane);
      b[mi] = frag_ld(Bt[cur], wc + mi * 16, 0, lane);
    }
    #pragma unroll
    for (int mi = 0; mi < 4; ++mi)
      #pragma unroll
      for (int ni = 0; ni < 4; ++ni)
        acc[mi][ni] = mfma16(a[mi], b[ni], acc[mi][ni]);
    #pragma unroll
    for (int mi = 0; mi < 4; ++mi) {
      a[mi] = frag_ld(At[cur], wr + mi * 16, 64, lane);
      b[mi] = frag_ld(Bt[cur], wc + mi * 16, 64, lane);
    }
    #pragma unroll
    for (int mi = 0; mi < 4; ++mi)
      #pragma unroll
      for (int ni = 0; ni < 4; ++ni)
        acc[mi][ni] = mfma16(a[mi], b[ni], acc[mi][ni]);
    BAR_FENCE();
    cur ^= 1;
  }
  #pragma unroll
  for (int ni = 0; ni < 4; ++ni) {
    float bv = bias[n0 + wc + ni * 16 + cl];
    #pragma unroll
    for (int mi = 0; mi < 4; ++mi)
      #pragma unroll
      for (int r = 0; r < 4; ++r) {
        int m = m0 + wr + mi * 16 + g * 4 + r;
        int n = n0 + wc + ni * 16 + cl;
        C[(size_t)m * D_ + n] = __float2bfloat16((acc[mi][ni][r] + bv) * scale);
      }
  }
}

// ---------------- pass 1 + vt_finalize fused.
__global__ __launch_bounds__(256, 4) void pass1vt(const __hip_bfloat16* __restrict__ Qb,
    const __hip_bfloat16* __restrict__ Kb, float* __restrict__ Lpart,
    const float* __restrict__ Vf_part, const float* __restrict__ bv,
    __hip_bfloat16* __restrict__ Vt) {
  __shared__ char Qt[128 * 128];
  __shared__ char Kt[2][64 * 128];
  __shared__ float partial[2][128];
  __shared__ float tt[32][33];
  const int tid = threadIdx.x, lane = tid & 63, wave = tid >> 6;

  if (blockIdx.x >= 1024) {
    // ---- vt_finalize path
    const int t2 = blockIdx.x - 1024;
    const int tx = tid & 31, ty = tid >> 5;
    const int c0 = (t2 & 1) * 32, r0 = (t2 >> 1) * 32;
    #pragma unroll
    for (int i = 0; i < 32; i += 8) {
      size_t idx = (size_t)(r0 + ty + i) * DK_ + c0 + tx;
      float s = bv[c0 + tx];
      #pragma unroll
      for (int p = 0; p < 8; ++p)
        s += Vf_part[idx + (size_t)p * (B_ * T_ * DK_)];
      tt[ty + i][tx] = s;
    }
    __syncthreads();
    #pragma unroll
    for (int i = 0; i < 32; i += 8)
      Vt[(size_t)(c0 + ty + i) * (B_ * T_) + r0 + tx] = __float2bfloat16(tt[tx][ty + i]);
    return;
  }

  const int id = xcd_swz<1024>(blockIdx.x);
  const int rt = id & 15, h = (id >> 4) & 15;
  const int b = (id >> 8) & 1, ch = id >> 9;
  const int row0 = rt * 128;
  const int cbase = ch * 16;   // 16 col-tiles of 64 each
  const int wr = (wave >> 1) * 64;
  const int wcid = wave & 1, wc = wcid * 32;
  stage_swz<128, 256>((const char*)(Qb + ((size_t)(b * T_ + row0) * D_ + h * DK_)), D_ * 2, Qt, tid);
  stage_swz<64, 256>((const char*)(Kb + ((size_t)(b * T_ + cbase * 64) * D_ + h * DK_)), D_ * 2, Kt[0], tid);
  __syncthreads();
  float rs[16] = {};
  int cur = 0;
  for (int ci = 0; ci < 16; ++ci) {
    if (ci + 1 < 16) {
      stage_swz<64, 256>((const char*)(Kb + ((size_t)(b * T_ + (cbase + ci + 1) * 64) * D_ + h * DK_)),
                         D_ * 2, Kt[cur ^ 1], tid);
      asm volatile("s_waitcnt vmcnt(2)" ::: "memory");
    } else {
      asm volatile("s_waitcnt vmcnt(0)" ::: "memory");
    }
    BAR_FENCE();
    bhalf8 a[4][2], bb[2][2];
    #pragma unroll
    for (int mi = 0; mi < 4; ++mi)
      #pragma unroll
      for (int ks = 0; ks < 2; ++ks)
        a[mi][ks] = frag_ld(Qt, wr + mi * 16, ks * 64, lane);
    #pragma unroll
    for (int ni = 0; ni < 2; ++ni)
      #pragma unroll
      for (int ks = 0; ks < 2; ++ks)
        bb[ni][ks] = frag_ld(Kt[cur], wc + ni * 16, ks * 64, lane);
    __builtin_amdgcn_s_setprio(1);
    #pragma unroll
    for (int mi = 0; mi < 4; ++mi)
      #pragma unroll
      for (int ni = 0; ni < 2; ++ni) {
        f32x4 s = {0.f, 0.f, 0.f, 0.f};
        s = mfma16(a[mi][0], bb[ni][0], s);
        s = mfma16(a[mi][1], bb[ni][1], s);
        #pragma unroll
        for (int r = 0; r < 4; ++r)
          rs[mi * 4 + r] += __builtin_amdgcn_exp2f(s[r]);
      }
    __builtin_amdgcn_s_setprio(0);
    BAR_FENCE();
    cur ^= 1;
  }
  #pragma unroll
  for (int off = 1; off < 16; off <<= 1)
    #pragma unroll
    for (int i = 0; i < 16; ++i)
      rs[i] += __shfl_xor(rs[i], off, 64);
  if ((lane & 15) == 0) {
    int g = lane >> 4;
    #pragma unroll
    for (int mi = 0; mi < 4; ++mi)
      #pragma unroll
      for (int r = 0; r < 4; ++r)
        partial[wcid][wr + mi * 16 + g * 4 + r] = rs[mi * 4 + r];
  }
  __syncthreads();
  if (tid < 128) {
    float s = partial[0][tid] + partial[1][tid];
    Lpart[(size_t)ch * (B_ * H_ * T_) + (size_t)(b * H_ + h) * T_ + row0 + tid] = s;
  }
}

// ---------------- pass 2: am tile = sum_h exp2(Qb.Kb) * linv, fused PV epilogue.
// Head loop: counted vmcnt(4) double-buffer; V-half0 prefetched under last head.
// PV result accumulated into single ctx via f32 atomics (ctx zeroed in prep).
__global__ __launch_bounds__(512, 4) void attn_pass2(const __hip_bfloat16* __restrict__ Qb,
    const __hip_bfloat16* __restrict__ Kb, const float* __restrict__ Lpart,
    const __hip_bfloat16* __restrict__ Vt, float* __restrict__ am,
    float* __restrict__ ctx) {
  __shared__ char Qt[2][128 * 128];
  __shared__ char Kt[2][128 * 128];
  __shared__ float linv[H_][128];
  const int tid = threadIdx.x, lane = tid & 63, wave = tid >> 6;
  const int id = xcd_swz<512>(blockIdx.x);
  const int col0 = (id & 15) * 128, row0 = ((id >> 4) & 15) * 128, b = id >> 8;
  const int wr = (wave >> 1) * 32, wc = (wave & 1) * 64;
  const int g = lane >> 4, cl = lane & 15;
  const size_t NBH = (size_t)B_ * H_ * T_;
  for (int i = tid; i < H_ * 128; i += 512) {
    int hh = i >> 7, r = i & 127;
    size_t idx = (size_t)(b * H_ + hh) * T_ + row0 + r;
    linv[hh][r] = 1.0f / (16.0f * (Lpart[idx] + Lpart[idx + NBH]));
  }
  stage_swz<128, 512>((const char*)(Qb + ((size_t)(b * T_ + row0) * D_)), D_ * 2, Qt[0], tid);
  stage_swz<128, 512>((const char*)(Kb + ((size_t)(b * T_ + col0) * D_)), D_ * 2, Kt[0], tid);
  __syncthreads();
  f32x4 acc[2][4] = {};
  int cur = 0;
  for (int h = 0; h < H_; ++h) {
    if (h + 1 < H_) {
      stage_swz<128, 512>((const char*)(Qb + ((size_t)(b * T_ + row0) * D_ + (h + 1) * DK_)),
                          D_ * 2, Qt[cur ^ 1], tid);
      stage_swz<128, 512>((const char*)(Kb + ((size_t)(b * T_ + col0) * D_ + (h + 1) * DK_)),
                          D_ * 2, Kt[cur ^ 1], tid);
      asm volatile("s_waitcnt vmcnt(4)" ::: "memory");
    } else {
      // Last head: prefetch V-half0 into the free Kt buffer (cur==1 here, so
      // Kt[0]); vmcnt(1) = all of stage(15) landed, V still in flight.
      stage_swz<64, 512>((const char*)Vt + (size_t)(b * T_ + col0) * 2, B_ * T_ * 2,
                         Kt[cur ^ 1], tid);
      asm volatile("s_waitcnt vmcnt(1)" ::: "memory");
    }
    BAR_FENCE();
    bhalf8 a[2][2], bb[4][2];
    #pragma unroll
    for (int mi = 0; mi < 2; ++mi)
      #pragma unroll
      for (int ks = 0; ks < 2; ++ks)
        a[mi][ks] = frag_ld(Qt[cur], wr + mi * 16, ks * 64, lane);
    #pragma unroll
    for (int ni = 0; ni < 4; ++ni)
      #pragma unroll
      for (int ks = 0; ks < 2; ++ks)
        bb[ni][ks] = frag_ld(Kt[cur], wc + ni * 16, ks * 64, lane);
    __builtin_amdgcn_s_setprio(1);
    #pragma unroll
    for (int mi = 0; mi < 2; ++mi) {
      f32x4 lv = *(const f32x4*)&linv[h][wr + mi * 16 + g * 4];
      #pragma unroll
      for (int ni = 0; ni < 4; ++ni) {
        f32x4 s = {0.f, 0.f, 0.f, 0.f};
        s = mfma16(a[mi][0], bb[ni][0], s);
        s = mfma16(a[mi][1], bb[ni][1], s);
        #pragma unroll
        for (int r = 0; r < 4; ++r)
          acc[mi][ni][r] += __builtin_amdgcn_exp2f(s[r]) * lv[r];
      }
    }
    __builtin_amdgcn_s_setprio(0);
    BAR_FENCE();
    cur ^= 1;
  }
  // ---- Fused PV epilogue ----
  // cur is back to 0; V-half0 already in (or landing in) Kt[0]. Stage half1.
  stage_swz<64, 512>((const char*)Vt + (size_t)(b * T_ + col0 + 64) * 2, B_ * T_ * 2, Kt[1], tid);
  #pragma unroll
  for (int mi = 0; mi < 2; ++mi)
    #pragma unroll
    for (int ni = 0; ni < 4; ++ni)
      #pragma unroll
      for (int r = 0; r < 4; ++r) {
        int row = wr + mi * 16 + g * 4 + r;
        int colL = wc + ni * 16 + cl;
        float v = acc[mi][ni][r];
        am[((size_t)(b * T_ + row0 + row)) * T_ + col0 + colL] = v;
        char* base = (colL & 64) ? Qt[1] : Qt[0];
        int within = colL & 63;
        int slot = within >> 3;
        *(__hip_bfloat16*)(base + row * 128 + (((slot ^ (row & 7)) << 4) | ((within & 7) * 2)))
            = __float2bfloat16(v);
      }
  __syncthreads();   // drains V loads + am LDS writes
  const int wr2 = (wave >> 1) * 32, wc2 = (wave & 1) * 32;
  f32x4 acc2[2][2] = {};
  __builtin_amdgcn_s_setprio(1);
  #pragma unroll
  for (int mi = 0; mi < 2; ++mi) {
    bhalf8 pa[4];
    #pragma unroll
    for (int kk = 0; kk < 4; ++kk)
      pa[kk] = frag_ld(Qt[kk >> 1], wr2 + mi * 16, (kk & 1) * 64, lane);
    #pragma unroll
    for (int ni = 0; ni < 2; ++ni) {
      #pragma unroll
      for (int kk = 0; kk < 4; ++kk) {
        bhalf8 pv = frag_ld(Kt[kk >> 1], wc2 + ni * 16, (kk & 1) * 64, lane);
        acc2[mi][ni] = mfma16(pa[kk], pv, acc2[mi][ni]);
      }
    }
  }
  __builtin_amdgcn_s_setprio(0);
  #pragma unroll
  for (int mi = 0; mi < 2; ++mi)
    #pragma unroll
    for (int ni = 0; ni < 2; ++ni)
      #pragma unroll
      for (int r = 0; r < 4; ++r) {
        int m = row0 + wr2 + mi * 16 + g * 4 + r;
        int n = wc2 + ni * 16 + cl;
        atomicAdd(&ctx[(size_t)(b * T_ + m) * DK_ + n], acc2[mi][ni][r]);
      }
}

// ---------------- out[4096][1024] = ctx @ Wo + bo  (K=64)
__global__ __launch_bounds__(256) void out_gemm(const float* __restrict__ ctx,
    const __hip_bfloat16* __restrict__ Wot, const float* __restrict__ bo,
    float* __restrict__ out) {
  __shared__ char At[128 * 128];
  __shared__ char Bt[128 * 128];
  const int tid = threadIdx.x, lane = tid & 63, wave = tid >> 6;
  const int m0 = blockIdx.x * 128, n0 = blockIdx.y * 128;
  const int wr = (wave >> 1) * 64, wc = (wave & 1) * 64;
  #pragma unroll
  for (int j = 0; j < 4; ++j) {
    int c = tid + j * 256;
    int row = c >> 3, slot = c & 7;
    const float* src = ctx + (size_t)(m0 + row) * DK_ + slot * 8;
    float f[8];
    *(float4*)f       = *(const float4*)src;
    *(float4*)(f + 4) = *(const float4*)(src + 4);
    cvt8_store(At, row, slot, f);
  }
  stage_swz<128, 256>((const char*)(Wot + (size_t)n0 * DK_), DK_ * 2, Bt, tid);
  __syncthreads();
  bhalf8 a[4][2], bb[4][2];
  #pragma unroll
  for (int mi = 0; mi < 4; ++mi)
    #pragma unroll
    for (int ks = 0; ks < 2; ++ks) {
      a[mi][ks]  = frag_ld(At, wr + mi * 16, ks * 64, lane);
      bb[mi][ks] = frag_ld(Bt, wc + mi * 16, ks * 64, lane);
    }
  f32x4 acc[4][4] = {};
  #pragma unroll
  for (int mi = 0; mi < 4; ++mi)
    #pragma unroll
    for (int ni = 0; ni < 4; ++ni) {
      acc[mi][ni] = mfma16(a[mi][0], bb[ni][0], acc[mi][ni]);
      acc[mi][ni] = mfma16(a[mi][1], bb[ni][1], acc[mi][ni]);
    }
  const int g = lane >> 4, cl = lane & 15;
  #pragma unroll
  for (int ni = 0; ni < 4; ++ni) {
    float bias = bo[n0 + wc + ni * 16 + cl];
    #pragma unroll
    for (int mi = 0; mi < 4; ++mi)
      #pragma unroll
      for (int r = 0; r < 4; ++r) {
        int m = m0 + wr + mi * 16 + g * 4 + r;
        int n = n0 + wc + ni * 16 + cl;
        out[(size_t)m * D_ + n] = acc[mi][ni][r] + bias;
      }
  }
}

extern "C" void kernel_launch(void* const* d_in, const int* in_sizes, int n_in,
                              void* d_out, int out_size, void* d_ws, size_t ws_size,
                              hipStream_t stream) {
  (void)in_sizes; (void)n_in; (void)out_size; (void)ws_size;
  const float* q  = (const float*)d_in[0];
  const float* k  = (const float*)d_in[1];
  const float* v  = (const float*)d_in[2];
  const float* Wq = (const float*)d_in[3];
  const float* bq = (const float*)d_in[4];
  const float* Wk = (const float*)d_in[5];
  const float* bk = (const float*)d_in[6];
  const float* Wv = (const float*)d_in[7];
  const float* bv = (const float*)d_in[8];
  const float* Wo = (const float*)d_in[9];
  const float* bo = (const float*)d_in[10];
  float* out = (float*)d_out;
  float* am  = out + (size_t)B_ * T_ * D_;   // attn_mean output region

  char* p = (char*)d_ws;
  __hip_bfloat16* qb  = (__hip_bfloat16*)p; p += (size_t)B_ * T_ * D_ * 2;
  __hip_bfloat16* kb  = (__hip_bfloat16*)p; p += (size_t)B_ * T_ * D_ * 2;
  __hip_bfloat16* Qb  = (__hip_bfloat16*)p; p += (size_t)B_ * T_ * D_ * 2;
  __hip_bfloat16* Kb  = (__hip_bfloat16*)p; p += (size_t)B_ * T_ * D_ * 2;
  __hip_bfloat16* Wqt = (__hip_bfloat16*)p; p += (size_t)D_ * D_ * 2;
  __hip_bfloat16* Wkt = (__hip_bfloat16*)p; p += (size_t)D_ * D_ * 2;
  __hip_bfloat16* Wot = (__hip_bfloat16*)p; p += (size_t)D_ * DK_ * 2;
  __hip_bfloat16* Wvt = (__hip_bfloat16*)p; p += (size_t)D_ * DK_ * 2;
  __hip_bfloat16* Vt  = (__hip_bfloat16*)p; p += (size_t)DK_ * B_ * T_ * 2;
  float* Lpart    = (float*)p; p += (size_t)2 * B_ * H_ * T_ * 4;
  float* ctx      = (float*)p; p += (size_t)B_ * T_ * DK_ * 4;
  float* Vf_part  = (float*)p; p += (size_t)8 * B_ * T_ * DK_ * 4;

  prep<<<dim3(6784), 256, 0, stream>>>(q, k, Wq, Wk, Wo, Wv, qb, kb, Wqt, Wkt,
                                       Wot, Wvt, ctx);

  // Softmax temperature baked into Qb: scores come out in exp2 domain.
  proj_all<<<dim3(256, 1, 3), 256, 0, stream>>>(qb, kb, v, Wqt, Wkt, Wvt, bq, bk,
                                                Qb, Kb, Vf_part);
  pass1vt<<<dim3(1280), 256, 0, stream>>>(Qb, Kb, Lpart, Vf_part, bv, Vt);
  attn_pass2<<<dim3(512), 512, 0, stream>>>(Qb, Kb, Lpart, Vt, am, ctx);

  out_gemm<<<dim3(32, 8), 256, 0, stream>>>(ctx, Wot, bo, out);
}

// Round 16
// 115.369 us; speedup vs baseline: 1.0220x; 1.0220x over previous
//
#include <hip/hip_runtime.h>
#include <hip/hip_bf16.h>

constexpr int B_  = 2;
constexpr int T_  = 2048;
constexpr int D_  = 1024;
constexpr int H_  = 16;
constexpr int DK_ = 64;
// exp(s/8) == exp2(s * log2(e)/8); this factor is baked into Qb.
#define SC_EXP 0.18033688011112042591f

typedef __attribute__((ext_vector_type(8))) short bhalf8;
typedef __attribute__((ext_vector_type(4))) float f32x4;

__device__ __forceinline__ f32x4 mfma16(bhalf8 a, bhalf8 b, f32x4 c) {
  return __builtin_amdgcn_mfma_f32_16x16x32_bf16(a, b, c, 0, 0, 0);
}

__device__ __forceinline__ void g2l16(const void* g, void* l) {
  __builtin_amdgcn_global_load_lds((const __attribute__((address_space(1))) void*)g,
                                   (__attribute__((address_space(3))) void*)l, 16, 0, 0);
}

// Raw barrier + scheduling fence (rule #18): no vmcnt drain.
#define BAR_FENCE() do { __builtin_amdgcn_s_barrier(); \
                         __builtin_amdgcn_sched_barrier(0); } while (0)

// XCD-aware bijective block swizzle (nwg must be a multiple of 8).
template<int NWG>
__device__ __forceinline__ int xcd_swz(int bid) {
  return (bid & 7) * (NWG / 8) + (bid >> 3);
}

// Stage ROWS x 128B (64 bf16) tile from global into LDS, slot-XOR swizzled.
// Source is pre-swizzled so the linear global_load_lds dest ends up swizzled.
template<int ROWS, int NT>
__device__ __forceinline__ void stage_swz(const char* gbase, int gstride,
                                          char* lds, int tid) {
  const int wave = tid >> 6;
  constexpr int CHUNKS = ROWS * 8;  // 16B chunks
  #pragma unroll
  for (int j = 0; j < CHUNKS / NT; ++j) {
    int c = j * NT + tid;
    int row = c >> 3, slot = c & 7;
    g2l16(gbase + (size_t)row * gstride + ((slot ^ (row & 7)) << 4),
          lds + (j * NT + wave * 64) * 16);
  }
}

// Read one 16x32 MFMA fragment (A or B^T layout) from a swizzled [rows][128B] tile.
__device__ __forceinline__ bhalf8 frag_ld(const char* tile, int row, int kbyte, int lane) {
  int r = row + (lane & 15);
  int off = kbyte + ((lane >> 4) << 4);
  off ^= (r & 7) << 4;
  return *(const bhalf8*)(tile + r * 128 + off);
}

// Convert 8 f32 -> bf16 and store to swizzled LDS tile position.
__device__ __forceinline__ void cvt8_store(char* lds, int row, int slot, const float* f) {
  union { bhalf8 v; __hip_bfloat16 h[8]; } u;
  #pragma unroll
  for (int i = 0; i < 8; ++i) u.h[i] = __float2bfloat16(f[i]);
  *(bhalf8*)(lds + row * 128 + ((slot ^ (row & 7)) << 4)) = u.v;
}

// ---------------- fused prep: q,k bf16 casts + 4 weight transposes.
__global__ __launch_bounds__(256) void prep(const float* __restrict__ q,
    const float* __restrict__ k, const float* __restrict__ Wq,
    const float* __restrict__ Wk, const float* __restrict__ Wo,
    const float* __restrict__ Wv, __hip_bfloat16* __restrict__ qb,
    __hip_bfloat16* __restrict__ kb, __hip_bfloat16* __restrict__ Wqt,
    __hip_bfloat16* __restrict__ Wkt, __hip_bfloat16* __restrict__ Wot,
    __hip_bfloat16* __restrict__ Wvt) {
  __shared__ float t[32][33];
  int bid = blockIdx.x;
  if (bid < 4096) {
    const float* s = bid < 2048 ? q : k;
    __hip_bfloat16* d = bid < 2048 ? qb : kb;
    int i = (bid & 2047) * 256 + threadIdx.x;
    const float4* sp = (const float4*)(s + (size_t)i * 8);
    float4 f0 = sp[0], f1 = sp[1];
    union { bhalf8 v; __hip_bfloat16 h[8]; } u;
    u.h[0] = __float2bfloat16(f0.x); u.h[1] = __float2bfloat16(f0.y);
    u.h[2] = __float2bfloat16(f0.z); u.h[3] = __float2bfloat16(f0.w);
    u.h[4] = __float2bfloat16(f1.x); u.h[5] = __float2bfloat16(f1.y);
    u.h[6] = __float2bfloat16(f1.z); u.h[7] = __float2bfloat16(f1.w);
    *(bhalf8*)(d + (size_t)i * 8) = u.v;
    return;
  }
  bid -= 4096;
  const float* src; __hip_bfloat16* dst; int R, C, bx, by;
  if (bid < 1024)      { src = Wq; dst = Wqt; R = 1024; C = 1024; bx = bid & 31; by = bid >> 5; }
  else if (bid < 2048) { bid -= 1024; src = Wk; dst = Wkt; R = 1024; C = 1024; bx = bid & 31; by = bid >> 5; }
  else if (bid < 2112) { bid -= 2048; src = Wo; dst = Wot; R = 64;   C = 1024; bx = bid & 31; by = bid >> 5; }
  else                 { bid -= 2112; src = Wv; dst = Wvt; R = 1024; C = 64;   bx = bid & 1;  by = bid >> 1; }
  const int tx = threadIdx.x & 31, ty = threadIdx.x >> 5;
  const int c0 = bx * 32, r0 = by * 32;
  #pragma unroll
  for (int i = 0; i < 32; i += 8)
    t[ty + i][tx] = src[(size_t)(r0 + ty + i) * C + c0 + tx];
  __syncthreads();
  #pragma unroll
  for (int i = 0; i < 32; i += 8)
    dst[(size_t)(c0 + ty + i) * R + r0 + tx] = __float2bfloat16(t[tx][ty + i]);
}

// ---------------- Q/K/V projections in ONE launch (blockIdx.z: 0=Q, 1=K, 2=V).
__global__ __launch_bounds__(256) void proj_all(const __hip_bfloat16* __restrict__ qb,
    const __hip_bfloat16* __restrict__ kb, const float* __restrict__ v,
    const __hip_bfloat16* __restrict__ Wqt, const __hip_bfloat16* __restrict__ Wkt,
    const __hip_bfloat16* __restrict__ Wvt, const float* __restrict__ bq,
    const float* __restrict__ bk, __hip_bfloat16* __restrict__ Qb,
    __hip_bfloat16* __restrict__ Kb, float* __restrict__ Vf_part) {
  __shared__ char At[2][128 * 128];
  __shared__ char Bt[2][128 * 128];
  const int tid = threadIdx.x, lane = tid & 63, wave = tid >> 6;
  const int g = lane >> 4, cl = lane & 15;

  if (blockIdx.z == 2) {
    // ---- V projection, split-K partials: Vf_part[ky][4096][64]
    const int m0 = (blockIdx.x & 31) * 128;
    const int ky = blockIdx.x >> 5;
    const int k0base = ky * 128;
    const int wr = (wave >> 1) * 64, wc = (wave & 1) * 32;
    stage_swz<64, 256>((const char*)(Wvt + k0base), D_ * 2, Bt[0], tid);
    stage_swz<64, 256>((const char*)(Wvt + k0base + 64), D_ * 2, Bt[1], tid);
    #pragma unroll
    for (int half = 0; half < 2; ++half) {
      const int k0 = k0base + half * 64;
      #pragma unroll
      for (int j = 0; j < 4; ++j) {
        int c = tid + j * 256;
        int row = c >> 3, slot = c & 7;
        const float* src = v + (size_t)(m0 + row) * D_ + k0 + slot * 8;
        float f[8];
        *(float4*)f       = *(const float4*)src;
        *(float4*)(f + 4) = *(const float4*)(src + 4);
        cvt8_store(At[half], row, slot, f);
      }
    }
    __syncthreads();
    f32x4 acc[4][2] = {};
    #pragma unroll
    for (int kk = 0; kk < 2; ++kk) {
      bhalf8 a[4][2], bb[2][2];
      #pragma unroll
      for (int mi = 0; mi < 4; ++mi)
        #pragma unroll
        for (int ks = 0; ks < 2; ++ks)
          a[mi][ks] = frag_ld(At[kk], wr + mi * 16, ks * 64, lane);
      #pragma unroll
      for (int ni = 0; ni < 2; ++ni)
        #pragma unroll
        for (int ks = 0; ks < 2; ++ks)
          bb[ni][ks] = frag_ld(Bt[kk], wc + ni * 16, ks * 64, lane);
      #pragma unroll
      for (int mi = 0; mi < 4; ++mi)
        #pragma unroll
        for (int ni = 0; ni < 2; ++ni) {
          acc[mi][ni] = mfma16(a[mi][0], bb[ni][0], acc[mi][ni]);
          acc[mi][ni] = mfma16(a[mi][1], bb[ni][1], acc[mi][ni]);
        }
    }
    float* dst = Vf_part + (size_t)ky * (B_ * T_ * DK_);
    #pragma unroll
    for (int mi = 0; mi < 4; ++mi)
      #pragma unroll
      for (int ni = 0; ni < 2; ++ni)
        #pragma unroll
        for (int r = 0; r < 4; ++r) {
          int m = m0 + wr + mi * 16 + g * 4 + r;
          int n = wc + ni * 16 + cl;
          dst[(size_t)m * DK_ + n] = acc[mi][ni][r];
        }
    return;
  }

  // ---- Q / K projection
  const bool isk = blockIdx.z != 0;
  const __hip_bfloat16* A  = isk ? kb : qb;
  const __hip_bfloat16* Wt = isk ? Wkt : Wqt;
  const float* bias        = isk ? bk : bq;
  __hip_bfloat16* C        = isk ? Kb : Qb;
  const float scale        = isk ? 1.0f : SC_EXP;
  const int id = xcd_swz<256>(blockIdx.x);
  const int m0 = (id & 31) * 128, n0 = (id >> 5) * 128;
  const int wr = (wave >> 1) * 64, wc = (wave & 1) * 64;
  f32x4 acc[4][4] = {};
  stage_swz<128, 256>((const char*)(A + (size_t)m0 * D_), D_ * 2, At[0], tid);
  stage_swz<128, 256>((const char*)(Wt + (size_t)n0 * D_), D_ * 2, Bt[0], tid);
  __syncthreads();
  int cur = 0;
  for (int k0 = 0; k0 < 16; ++k0) {
    if (k0 + 1 < 16) {
      stage_swz<128, 256>((const char*)(A + (size_t)m0 * D_ + (k0 + 1) * 64), D_ * 2, At[cur ^ 1], tid);
      stage_swz<128, 256>((const char*)(Wt + (size_t)n0 * D_ + (k0 + 1) * 64), D_ * 2, Bt[cur ^ 1], tid);
      asm volatile("s_waitcnt vmcnt(8)" ::: "memory");
    } else {
      asm volatile("s_waitcnt vmcnt(0)" ::: "memory");
    }
    BAR_FENCE();
    bhalf8 a[4], b[4];
    #pragma unroll
    for (int mi = 0; mi < 4; ++mi) {
      a[mi] = frag_ld(At[cur], wr + mi * 16, 0, lane);
      b[mi] = frag_ld(Bt[cur], wc + mi * 16, 0, lane);
    }
    #pragma unroll
    for (int mi = 0; mi < 4; ++mi)
      #pragma unroll
      for (int ni = 0; ni < 4; ++ni)
        acc[mi][ni] = mfma16(a[mi], b[ni], acc[mi][ni]);
    #pragma unroll
    for (int mi = 0; mi < 4; ++mi) {
      a[mi] = frag_ld(At[cur], wr + mi * 16, 64, lane);
      b[mi] = frag_ld(Bt[cur], wc + mi * 16, 64, lane);
    }
    #pragma unroll
    for (int mi = 0; mi < 4; ++mi)
      #pragma unroll
      for (int ni = 0; ni < 4; ++ni)
        acc[mi][ni] = mfma16(a[mi], b[ni], acc[mi][ni]);
    BAR_FENCE();
    cur ^= 1;
  }
  #pragma unroll
  for (int ni = 0; ni < 4; ++ni) {
    float bv = bias[n0 + wc + ni * 16 + cl];
    #pragma unroll
    for (int mi = 0; mi < 4; ++mi)
      #pragma unroll
      for (int r = 0; r < 4; ++r) {
        int m = m0 + wr + mi * 16 + g * 4 + r;
        int n = n0 + wc + ni * 16 + cl;
        C[(size_t)m * D_ + n] = __float2bfloat16((acc[mi][ni][r] + bv) * scale);
      }
  }
}

// ---------------- pass 1 + vt_finalize fused.
// Blocks [0,1024): Lpart[ch][b,h,t] = partial col-sums of exp2(Qb.Kb).
// Blocks [1024,1280): Vt[n][m] = bf16(sum_s Vf_part[s][m][n] + bv[n]).
__global__ __launch_bounds__(256, 4) void pass1vt(const __hip_bfloat16* __restrict__ Qb,
    const __hip_bfloat16* __restrict__ Kb, float* __restrict__ Lpart,
    const float* __restrict__ Vf_part, const float* __restrict__ bv,
    __hip_bfloat16* __restrict__ Vt) {
  __shared__ char Qt[128 * 128];
  __shared__ char Kt[2][64 * 128];
  __shared__ float partial[2][128];
  __shared__ float tt[32][33];
  const int tid = threadIdx.x, lane = tid & 63, wave = tid >> 6;

  if (blockIdx.x >= 1024) {
    // ---- vt_finalize path
    const int t2 = blockIdx.x - 1024;
    const int tx = tid & 31, ty = tid >> 5;
    const int c0 = (t2 & 1) * 32, r0 = (t2 >> 1) * 32;
    #pragma unroll
    for (int i = 0; i < 32; i += 8) {
      size_t idx = (size_t)(r0 + ty + i) * DK_ + c0 + tx;
      float s = bv[c0 + tx];
      #pragma unroll
      for (int p = 0; p < 8; ++p)
        s += Vf_part[idx + (size_t)p * (B_ * T_ * DK_)];
      tt[ty + i][tx] = s;
    }
    __syncthreads();
    #pragma unroll
    for (int i = 0; i < 32; i += 8)
      Vt[(size_t)(c0 + ty + i) * (B_ * T_) + r0 + tx] = __float2bfloat16(tt[tx][ty + i]);
    return;
  }

  const int id = xcd_swz<1024>(blockIdx.x);
  const int rt = id & 15, h = (id >> 4) & 15;
  const int b = (id >> 8) & 1, ch = id >> 9;
  const int row0 = rt * 128;
  const int cbase = ch * 16;   // 16 col-tiles of 64 each
  const int wr = (wave >> 1) * 64;
  const int wcid = wave & 1, wc = wcid * 32;
  stage_swz<128, 256>((const char*)(Qb + ((size_t)(b * T_ + row0) * D_ + h * DK_)), D_ * 2, Qt, tid);
  stage_swz<64, 256>((const char*)(Kb + ((size_t)(b * T_ + cbase * 64) * D_ + h * DK_)), D_ * 2, Kt[0], tid);
  __syncthreads();
  float rs[16] = {};
  int cur = 0;
  for (int ci = 0; ci < 16; ++ci) {
    if (ci + 1 < 16) {
      stage_swz<64, 256>((const char*)(Kb + ((size_t)(b * T_ + (cbase + ci + 1) * 64) * D_ + h * DK_)),
                         D_ * 2, Kt[cur ^ 1], tid);
      asm volatile("s_waitcnt vmcnt(2)" ::: "memory");
    } else {
      asm volatile("s_waitcnt vmcnt(0)" ::: "memory");
    }
    BAR_FENCE();
    bhalf8 a[4][2], bb[2][2];
    #pragma unroll
    for (int mi = 0; mi < 4; ++mi)
      #pragma unroll
      for (int ks = 0; ks < 2; ++ks)
        a[mi][ks] = frag_ld(Qt, wr + mi * 16, ks * 64, lane);
    #pragma unroll
    for (int ni = 0; ni < 2; ++ni)
      #pragma unroll
      for (int ks = 0; ks < 2; ++ks)
        bb[ni][ks] = frag_ld(Kt[cur], wc + ni * 16, ks * 64, lane);
    __builtin_amdgcn_s_setprio(1);
    #pragma unroll
    for (int mi = 0; mi < 4; ++mi)
      #pragma unroll
      for (int ni = 0; ni < 2; ++ni) {
        f32x4 s = {0.f, 0.f, 0.f, 0.f};
        s = mfma16(a[mi][0], bb[ni][0], s);
        s = mfma16(a[mi][1], bb[ni][1], s);
        #pragma unroll
        for (int r = 0; r < 4; ++r)
          rs[mi * 4 + r] += __builtin_amdgcn_exp2f(s[r]);
      }
    __builtin_amdgcn_s_setprio(0);
    BAR_FENCE();
    cur ^= 1;
  }
  #pragma unroll
  for (int off = 1; off < 16; off <<= 1)
    #pragma unroll
    for (int i = 0; i < 16; ++i)
      rs[i] += __shfl_xor(rs[i], off, 64);
  if ((lane & 15) == 0) {
    int g = lane >> 4;
    #pragma unroll
    for (int mi = 0; mi < 4; ++mi)
      #pragma unroll
      for (int r = 0; r < 4; ++r)
        partial[wcid][wr + mi * 16 + g * 4 + r] = rs[mi * 4 + r];
  }
  __syncthreads();
  if (tid < 128) {
    float s = partial[0][tid] + partial[1][tid];
    Lpart[(size_t)ch * (B_ * H_ * T_) + (size_t)(b * H_ + h) * T_ + row0 + tid] = s;
  }
}

// ---------------- pass 2: am tile = sum_h exp2(Qb.Kb) * linv, fused PV epilogue.
// Head loop: counted vmcnt(4) double-buffer.
__global__ __launch_bounds__(512, 4) void attn_pass2(const __hip_bfloat16* __restrict__ Qb,
    const __hip_bfloat16* __restrict__ Kb, const float* __restrict__ Lpart,
    const __hip_bfloat16* __restrict__ Vt, float* __restrict__ am,
    float* __restrict__ ctx_part) {
  __shared__ char Qt[2][128 * 128];
  __shared__ char Kt[2][128 * 128];
  __shared__ float linv[H_][128];
  const int tid = threadIdx.x, lane = tid & 63, wave = tid >> 6;
  const int id = xcd_swz<512>(blockIdx.x);
  const int col0 = (id & 15) * 128, row0 = ((id >> 4) & 15) * 128, b = id >> 8;
  const int wr = (wave >> 1) * 32, wc = (wave & 1) * 64;
  const int g = lane >> 4, cl = lane & 15;
  const size_t NBH = (size_t)B_ * H_ * T_;
  for (int i = tid; i < H_ * 128; i += 512) {
    int hh = i >> 7, r = i & 127;
    size_t idx = (size_t)(b * H_ + hh) * T_ + row0 + r;
    linv[hh][r] = 1.0f / (16.0f * (Lpart[idx] + Lpart[idx + NBH]));
  }
  stage_swz<128, 512>((const char*)(Qb + ((size_t)(b * T_ + row0) * D_)), D_ * 2, Qt[0], tid);
  stage_swz<128, 512>((const char*)(Kb + ((size_t)(b * T_ + col0) * D_)), D_ * 2, Kt[0], tid);
  __syncthreads();
  f32x4 acc[2][4] = {};
  int cur = 0;
  for (int h = 0; h < H_; ++h) {
    if (h + 1 < H_) {
      stage_swz<128, 512>((const char*)(Qb + ((size_t)(b * T_ + row0) * D_ + (h + 1) * DK_)),
                          D_ * 2, Qt[cur ^ 1], tid);
      stage_swz<128, 512>((const char*)(Kb + ((size_t)(b * T_ + col0) * D_ + (h + 1) * DK_)),
                          D_ * 2, Kt[cur ^ 1], tid);
      asm volatile("s_waitcnt vmcnt(4)" ::: "memory");
    } else {
      asm volatile("s_waitcnt vmcnt(0)" ::: "memory");
    }
    BAR_FENCE();
    bhalf8 a[2][2], bb[4][2];
    #pragma unroll
    for (int mi = 0; mi < 2; ++mi)
      #pragma unroll
      for (int ks = 0; ks < 2; ++ks)
        a[mi][ks] = frag_ld(Qt[cur], wr + mi * 16, ks * 64, lane);
    #pragma unroll
    for (int ni = 0; ni < 4; ++ni)
      #pragma unroll
      for (int ks = 0; ks < 2; ++ks)
        bb[ni][ks] = frag_ld(Kt[cur], wc + ni * 16, ks * 64, lane);
    __builtin_amdgcn_s_setprio(1);
    #pragma unroll
    for (int mi = 0; mi < 2; ++mi) {
      f32x4 lv = *(const f32x4*)&linv[h][wr + mi * 16 + g * 4];
      #pragma unroll
      for (int ni = 0; ni < 4; ++ni) {
        f32x4 s = {0.f, 0.f, 0.f, 0.f};
        s = mfma16(a[mi][0], bb[ni][0], s);
        s = mfma16(a[mi][1], bb[ni][1], s);
        #pragma unroll
        for (int r = 0; r < 4; ++r)
          acc[mi][ni][r] += __builtin_amdgcn_exp2f(s[r]) * lv[r];
      }
    }
    __builtin_amdgcn_s_setprio(0);
    BAR_FENCE();
    cur ^= 1;
  }
  // ---- Fused PV epilogue ----
  stage_swz<64, 512>((const char*)Vt + (size_t)(b * T_ + col0) * 2, B_ * T_ * 2, Kt[0], tid);
  stage_swz<64, 512>((const char*)Vt + (size_t)(b * T_ + col0 + 64) * 2, B_ * T_ * 2, Kt[1], tid);
  #pragma unroll
  for (int mi = 0; mi < 2; ++mi)
    #pragma unroll
    for (int ni = 0; ni < 4; ++ni)
      #pragma unroll
      for (int r = 0; r < 4; ++r) {
        int row = wr + mi * 16 + g * 4 + r;
        int colL = wc + ni * 16 + cl;
        float v = acc[mi][ni][r];
        am[((size_t)(b * T_ + row0 + row)) * T_ + col0 + colL] = v;
        char* base = (colL & 64) ? Qt[1] : Qt[0];
        int within = colL & 63;
        int slot = within >> 3;
        *(__hip_bfloat16*)(base + row * 128 + (((slot ^ (row & 7)) << 4) | ((within & 7) * 2)))
            = __float2bfloat16(v);
      }
  __syncthreads();
  const int wr2 = (wave >> 1) * 32, wc2 = (wave & 1) * 32;
  f32x4 acc2[2][2] = {};
  __builtin_amdgcn_s_setprio(1);
  #pragma unroll
  for (int mi = 0; mi < 2; ++mi) {
    bhalf8 pa[4];
    #pragma unroll
    for (int kk = 0; kk < 4; ++kk)
      pa[kk] = frag_ld(Qt[kk >> 1], wr2 + mi * 16, (kk & 1) * 64, lane);
    #pragma unroll
    for (int ni = 0; ni < 2; ++ni) {
      #pragma unroll
      for (int kk = 0; kk < 4; ++kk) {
        bhalf8 pv = frag_ld(Kt[kk >> 1], wc2 + ni * 16, (kk & 1) * 64, lane);
        acc2[mi][ni] = mfma16(pa[kk], pv, acc2[mi][ni]);
      }
    }
  }
  __builtin_amdgcn_s_setprio(0);
  float* dst = ctx_part + (size_t)(id & 15) * (B_ * T_ * DK_);
  #pragma unroll
  for (int mi = 0; mi < 2; ++mi)
    #pragma unroll
    for (int ni = 0; ni < 2; ++ni)
      #pragma unroll
      for (int r = 0; r < 4; ++r) {
        int m = row0 + wr2 + mi * 16 + g * 4 + r;
        int n = wc2 + ni * 16 + cl;
        dst[(size_t)(b * T_ + m) * DK_ + n] = acc2[mi][ni][r];
      }
}

// ---------------- out[4096][1024] = (sum_s ctx_part[s]) @ Wo + bo  (K=64)
__global__ __launch_bounds__(256) void out_gemm(const float* __restrict__ ctx_part,
    const __hip_bfloat16* __restrict__ Wot, const float* __restrict__ bo,
    float* __restrict__ out) {
  __shared__ char At[128 * 128];
  __shared__ char Bt[128 * 128];
  const int tid = threadIdx.x, lane = tid & 63, wave = tid >> 6;
  const int m0 = blockIdx.x * 128, n0 = blockIdx.y * 128;
  const int wr = (wave >> 1) * 64, wc = (wave & 1) * 64;
  #pragma unroll
  for (int j = 0; j < 4; ++j) {
    int c = tid + j * 256;
    int row = c >> 3, slot = c & 7;
    size_t base = (size_t)(m0 + row) * DK_ + slot * 8;
    float f[8] = {};
    #pragma unroll
    for (int p = 0; p < 16; ++p) {
      const float* src = ctx_part + base + (size_t)p * (B_ * T_ * DK_);
      float4 s0 = *(const float4*)src;
      float4 s1 = *(const float4*)(src + 4);
      f[0] += s0.x; f[1] += s0.y; f[2] += s0.z; f[3] += s0.w;
      f[4] += s1.x; f[5] += s1.y; f[6] += s1.z; f[7] += s1.w;
    }
    cvt8_store(At, row, slot, f);
  }
  stage_swz<128, 256>((const char*)(Wot + (size_t)n0 * DK_), DK_ * 2, Bt, tid);
  __syncthreads();
  bhalf8 a[4][2], bb[4][2];
  #pragma unroll
  for (int mi = 0; mi < 4; ++mi)
    #pragma unroll
    for (int ks = 0; ks < 2; ++ks) {
      a[mi][ks]  = frag_ld(At, wr + mi * 16, ks * 64, lane);
      bb[mi][ks] = frag_ld(Bt, wc + mi * 16, ks * 64, lane);
    }
  f32x4 acc[4][4] = {};
  #pragma unroll
  for (int mi = 0; mi < 4; ++mi)
    #pragma unroll
    for (int ni = 0; ni < 4; ++ni) {
      acc[mi][ni] = mfma16(a[mi][0], bb[ni][0], acc[mi][ni]);
      acc[mi][ni] = mfma16(a[mi][1], bb[ni][1], acc[mi][ni]);
    }
  const int g = lane >> 4, cl = lane & 15;
  #pragma unroll
  for (int ni = 0; ni < 4; ++ni) {
    float bias = bo[n0 + wc + ni * 16 + cl];
    #pragma unroll
    for (int mi = 0; mi < 4; ++mi)
      #pragma unroll
      for (int r = 0; r < 4; ++r) {
        int m = m0 + wr + mi * 16 + g * 4 + r;
        int n = n0 + wc + ni * 16 + cl;
        out[(size_t)m * D_ + n] = acc[mi][ni][r] + bias;
      }
  }
}

extern "C" void kernel_launch(void* const* d_in, const int* in_sizes, int n_in,
                              void* d_out, int out_size, void* d_ws, size_t ws_size,
                              hipStream_t stream) {
  (void)in_sizes; (void)n_in; (void)out_size; (void)ws_size;
  const float* q  = (const float*)d_in[0];
  const float* k  = (const float*)d_in[1];
  const float* v  = (const float*)d_in[2];
  const float* Wq = (const float*)d_in[3];
  const float* bq = (const float*)d_in[4];
  const float* Wk = (const float*)d_in[5];
  const float* bk = (const float*)d_in[6];
  const float* Wv = (const float*)d_in[7];
  const float* bv = (const float*)d_in[8];
  const float* Wo = (const float*)d_in[9];
  const float* bo = (const float*)d_in[10];
  float* out = (float*)d_out;
  float* am  = out + (size_t)B_ * T_ * D_;   // attn_mean output region

  char* p = (char*)d_ws;
  __hip_bfloat16* qb  = (__hip_bfloat16*)p; p += (size_t)B_ * T_ * D_ * 2;
  __hip_bfloat16* kb  = (__hip_bfloat16*)p; p += (size_t)B_ * T_ * D_ * 2;
  __hip_bfloat16* Qb  = (__hip_bfloat16*)p; p += (size_t)B_ * T_ * D_ * 2;
  __hip_bfloat16* Kb  = (__hip_bfloat16*)p; p += (size_t)B_ * T_ * D_ * 2;
  __hip_bfloat16* Wqt = (__hip_bfloat16*)p; p += (size_t)D_ * D_ * 2;
  __hip_bfloat16* Wkt = (__hip_bfloat16*)p; p += (size_t)D_ * D_ * 2;
  __hip_bfloat16* Wot = (__hip_bfloat16*)p; p += (size_t)D_ * DK_ * 2;
  __hip_bfloat16* Wvt = (__hip_bfloat16*)p; p += (size_t)D_ * DK_ * 2;
  __hip_bfloat16* Vt  = (__hip_bfloat16*)p; p += (size_t)DK_ * B_ * T_ * 2;
  float* Lpart    = (float*)p; p += (size_t)2 * B_ * H_ * T_ * 4;
  float* ctx_part = (float*)p; p += (size_t)16 * B_ * T_ * DK_ * 4;
  float* Vf_part  = (float*)p; p += (size_t)8 * B_ * T_ * DK_ * 4;

  prep<<<dim3(6272), 256, 0, stream>>>(q, k, Wq, Wk, Wo, Wv, qb, kb, Wqt, Wkt, Wot, Wvt);

  // Softmax temperature baked into Qb: scores come out in exp2 domain.
  proj_all<<<dim3(256, 1, 3), 256, 0, stream>>>(qb, kb, v, Wqt, Wkt, Wvt, bq, bk,
                                                Qb, Kb, Vf_part);
  pass1vt<<<dim3(1280), 256, 0, stream>>>(Qb, Kb, Lpart, Vf_part, bv, Vt);
  attn_pass2<<<dim3(512), 512, 0, stream>>>(Qb, Kb, Lpart, Vt, am, ctx_part);

  out_gemm<<<dim3(32, 8), 256, 0, stream>>>(ctx_part, Wot, bo, out);
}